// Round 1
// 427.438 us; speedup vs baseline: 1.0697x; 1.0697x over previous
//
#include <hip/hip_runtime.h>
#include <stdint.h>

#define NN 100000   // nodes
#define NK 10       // sampled neighbors
#define D  256      // hidden dim
#define D2 512      // concat dim
#define MT 32       // nodes per block; 100000/32 = 3125 exactly -> no tails

typedef short bf16x8 __attribute__((ext_vector_type(8)));   // 8 bf16 (4 VGPRs)
typedef float f32x4  __attribute__((ext_vector_type(4)));

__device__ __forceinline__ uint16_t f2bf(float f) {
  uint32_t u = __float_as_uint(f);
  u += 0x7fffu + ((u >> 16) & 1u);   // round-to-nearest-even
  return (uint16_t)(u >> 16);
}
__device__ __forceinline__ uint32_t pack2(float a, float b) {
  return (uint32_t)f2bf(a) | ((uint32_t)f2bf(b) << 16);
}

// ---------------------------------------------------------------------------
// prep: fused {3x pack_w , quant_x} in one launch (saves 3 kernel launches).
// blocks [0,192): pack W0/W1/W2 into bf16 MFMA B-fragment order.
// blocks [192, 192+NN/4): int8-quantize x rows (one wave per row).
// ---------------------------------------------------------------------------
__global__ __launch_bounds__(256) void prep(
    const float* __restrict__ x, uint8_t* __restrict__ q8, float* __restrict__ qs,
    const float* __restrict__ W0, const float* __restrict__ W1,
    const float* __restrict__ W2, uint16_t* __restrict__ Wp0,
    uint16_t* __restrict__ Wp1, uint16_t* __restrict__ Wp2)
{
  const int bid = blockIdx.x;
  if (bid < 192) {
    const float* W;
    uint16_t* Wp;
    if (bid < 64)       { W = W0; Wp = Wp0; }
    else if (bid < 128) { W = W1; Wp = Wp1; }
    else                { W = W2; Wp = Wp2; }
    int idx   = ((bid & 63) << 8) + threadIdx.x;   // 0..16383
    int lane  = idx & 63;
    int ntile = (idx >> 6) & 15;
    int kstep = idx >> 10;
    int n  = ntile * 16 + (lane & 15);
    int k0 = kstep * 32 + (lane >> 4) * 8;
    float v[8];
#pragma unroll
    for (int j = 0; j < 8; j++) v[j] = W[(size_t)(k0 + j) * D + n];
    uint4 o;
    o.x = pack2(v[0], v[1]);
    o.y = pack2(v[2], v[3]);
    o.z = pack2(v[4], v[5]);
    o.w = pack2(v[6], v[7]);
    ((uint4*)Wp)[idx] = o;
  } else {
    int node = (bid - 192) * 4 + (threadIdx.x >> 6);
    int lane = threadIdx.x & 63;
    const float4 v = *(const float4*)(x + (size_t)node * D + lane * 4);
    float m = fmaxf(fmaxf(fabsf(v.x), fabsf(v.y)), fmaxf(fabsf(v.z), fabsf(v.w)));
#pragma unroll
    for (int d = 1; d < 64; d <<= 1) m = fmaxf(m, __shfl_xor(m, d, 64));
    float inv = m > 1e-30f ? 127.0f / m : 0.0f;
    int q0 = (int)rintf(v.x * inv), q1 = (int)rintf(v.y * inv);
    int q2 = (int)rintf(v.z * inv), q3 = (int)rintf(v.w * inv);
    uint32_t p = (uint32_t)(q0 & 0xff) | ((uint32_t)(q1 & 0xff) << 8) |
                 ((uint32_t)(q2 & 0xff) << 16) | ((uint32_t)(q3 & 0xff) << 24);
    ((uint32_t*)(q8 + (size_t)node * D))[lane] = p;
    if (lane == 0) qs[node] = m * (1.0f / 127.0f);
  }
}

// ---------------------------------------------------------------------------
// Fused SAGE layer, v2: latency-pipelined gather.
//  - adj for the wave's 8 rows hoisted to 4 coalesced register loads at wave
//    start, broadcast at use via __shfl (kills the adj->qtab serial chain).
//  - gather software-pipelined 2-deep with double-buffered register staging:
//    issue iter i+1's 20 loads before dequantizing iter i (in-order vmcnt
//    keeps the younger buffer in flight across the older buffer's consume).
//  - bf16 layers: self rows loaded to regs first, LDS writes deferred until
//    after the first two gather issues -> self + 40 gather loads co-in-flight.
// Numerics identical to v1 (same quant, same FMA order) -> absmax unchanged.
// LDS: 32 rows x 512 k bf16 = 32 KB. XOR swizzle on 16B chunks (0 conflicts).
// VGPRs ~100 (staging 60 + acc) -> __launch_bounds__(256,4): 16 waves/CU.
// ---------------------------------------------------------------------------
template <bool SELF_F32, bool QOUT>
__global__ __launch_bounds__(256, 4) void sage_layer(
    const void*     __restrict__ hin_v,  // self table: f32 or bf16 [NN][D]
    const uint8_t*  __restrict__ qtab,   // gather table int8 [NN][D]
    const float*    __restrict__ qsc,    // [NN] gather row scales
    const int*      __restrict__ adj,    // [NN][NK]
    const uint16_t* __restrict__ Wp,     // packed bf16 W [16][16][64][8]
    const float*    __restrict__ bias,   // [D] f32
    void*           __restrict__ hout_v, // bf16 (QOUT) / f32 (!QOUT)
    uint8_t*        __restrict__ q8out,  // int8 table out (QOUT)
    float*          __restrict__ qsout)  // row scales out (QOUT)
{
  __shared__ uint4 lds4[MT * 64];        // 32 rows * 64 chunks * 16B = 32 KB
  const int t    = threadIdx.x;
  const int m0   = blockIdx.x * MT;
  const int half = t >> 5;               // 0..7; wave w owns halves 2w, 2w+1
  const int l32  = t & 31;
  const int hb   = half & ~1;            // wave's row-pair base
  const int hsel = (half & 1) * 10;      // adj-entry offset for this half

  // ---- adj for this wave's 8 rows: 4 x 80B coalesced loads, issued first ----
  // av_i[lane l32<20] = adj[(m0 + i*8 + hb)*NK + l32]  (rows hb: 0..9, hb+1: 10..19)
  int av0, av1, av2, av3;
  {
    const int* ap = adj + (size_t)(m0 + hb) * NK;
    int o = (l32 < 20) ? l32 : 0;
    av0 = ap[o];
    av1 = ap[80 + o];
    av2 = ap[160 + o];
    av3 = ap[240 + o];
  }

  // gather staging (double-buffered; all indexing compile-time -> registers)
  uint2 gA[NK], gB[NK];
  float sA[NK], sB[NK];

  auto issue = [&](int av, uint2 (&g)[NK], float (&s)[NK]) {
#pragma unroll
    for (int k = 0; k < NK; k++) {
      int nb = __shfl(av, hsel + k, 32);     // broadcast within 32-lane half
      s[k] = qsc[nb];
      g[k] = *(const uint2*)(qtab + (size_t)nb * D + l32 * 8);
    }
  };
  auto consume = [&](const uint2 (&g)[NK], const float (&s)[NK], int i) {
    int r = i * 8 + half;
    float a0=0.f,a1=0.f,a2=0.f,a3=0.f,a4=0.f,a5=0.f,a6=0.f,a7=0.f;
#pragma unroll
    for (int k = 0; k < NK; k++) {
      float sk = s[k];
      uint2 v  = g[k];
      a0 += sk * (float)(int8_t)(v.x);
      a1 += sk * (float)(int8_t)(v.x >> 8);
      a2 += sk * (float)(int8_t)(v.x >> 16);
      a3 += sk * (float)(int8_t)(v.x >> 24);
      a4 += sk * (float)(int8_t)(v.y);
      a5 += sk * (float)(int8_t)(v.y >> 8);
      a6 += sk * (float)(int8_t)(v.y >> 16);
      a7 += sk * (float)(int8_t)(v.y >> 24);
    }
    const float sc = 1.0f / (float)NK;
    uint4 o;
    o.x = pack2(a0 * sc, a1 * sc);
    o.y = pack2(a2 * sc, a3 * sc);
    o.z = pack2(a4 * sc, a5 * sc);
    o.w = pack2(a6 * sc, a7 * sc);
    int c = 32 + l32;
    lds4[r * 64 + (c ^ (r & 15))] = o;
  };

  // ---- phase 1 (self rows -> chunks 0..31) interleaved with gather issue ----
  if constexpr (SELF_F32) {
    // layer 0: f32 self rows are register-heavy; write-as-loaded, then pipeline
#pragma unroll
    for (int i = 0; i < 4; i++) {
      int cidx = t + i * 256;
      int r = cidx >> 5, c = cidx & 31;
      const float4* p =
          (const float4*)((const float*)hin_v + (size_t)(m0 + r) * D + c * 8);
      float4 v0 = p[0], v1 = p[1];
      uint4 o;
      o.x = pack2(v0.x, v0.y); o.y = pack2(v0.z, v0.w);
      o.z = pack2(v1.x, v1.y); o.w = pack2(v1.z, v1.w);
      lds4[r * 64 + (c ^ (r & 15))] = o;
    }
    issue(av0, gA, sA);
    issue(av1, gB, sB);
  } else {
    // bf16 layers: load self rows to regs, start gather, then LDS-write
    uint4 p1[4];
#pragma unroll
    for (int i = 0; i < 4; i++) {
      int cidx = t + i * 256;
      int r = cidx >> 5, c = cidx & 31;
      p1[i] = *(const uint4*)((const uint16_t*)hin_v + (size_t)(m0 + r) * D + c * 8);
    }
    issue(av0, gA, sA);
    issue(av1, gB, sB);
#pragma unroll
    for (int i = 0; i < 4; i++) {
      int cidx = t + i * 256;
      int r = cidx >> 5, c = cidx & 31;
      lds4[r * 64 + (c ^ (r & 15))] = p1[i];
    }
  }

  // ---- phase 2: 2-deep pipelined gather-mean -> chunks 32..63 ----
  consume(gA, sA, 0);
  issue(av2, gA, sA);
  consume(gB, sB, 1);
  issue(av3, gB, sB);
  consume(gA, sA, 2);
  consume(gB, sB, 3);

  __syncthreads();

  // ---- phase 3: GEMM  [32 x 512] @ [512 x 256] ----
  const int w    = t >> 6;   // wave 0..3 -> output cols w*64 .. w*64+63
  const int l    = t & 63;
  const int quad = l >> 4;
  const int l16  = l & 15;

  f32x4 acc[2][4];
#pragma unroll
  for (int mt = 0; mt < 2; mt++)
#pragma unroll
    for (int nt = 0; nt < 4; nt++)
      acc[mt][nt] = (f32x4){0.f, 0.f, 0.f, 0.f};

  const uint4* wp4 = (const uint4*)Wp;

#pragma unroll 2
  for (int ks = 0; ks < 16; ks++) {
    bf16x8 af[2], bfr[4];
#pragma unroll
    for (int mt = 0; mt < 2; mt++) {
      int row = mt * 16 + l16;                 // A: m = lane&15
      int c   = ks * 4 + quad;                 // A: k = quad*8 + j
      af[mt] = *((const bf16x8*)&lds4[row * 64 + (c ^ (row & 15))]);
    }
#pragma unroll
    for (int nt = 0; nt < 4; nt++) {
      bfr[nt] = *((const bf16x8*)&wp4[(ks * 16 + (w * 4 + nt)) * 64 + l]);
    }
#pragma unroll
    for (int mt = 0; mt < 2; mt++)
#pragma unroll
      for (int nt = 0; nt < 4; nt++)
        acc[mt][nt] = __builtin_amdgcn_mfma_f32_16x16x32_bf16(
            af[mt], bfr[nt], acc[mt][nt], 0, 0, 0);
  }

  // ---- epilogue: bias (+ReLU), row-scale quant (QOUT), store ----
  float lmax[2][4];
#pragma unroll
  for (int mt = 0; mt < 2; mt++)
#pragma unroll
    for (int i = 0; i < 4; i++) lmax[mt][i] = 0.0f;

#pragma unroll
  for (int mt = 0; mt < 2; mt++)
#pragma unroll
    for (int nt = 0; nt < 4; nt++)
#pragma unroll
      for (int i = 0; i < 4; i++) {
        int col = w * 64 + nt * 16 + l16;      // C/D: col = lane&15
        float v = acc[mt][nt][i] + bias[col];
        if (QOUT) v = fmaxf(v, 0.0f);          // ReLU on layers 0,1
        acc[mt][nt][i] = v;
        if (QOUT) lmax[mt][i] = fmaxf(lmax[mt][i], v);
      }

  float inv[2][4];
  if (QOUT) {
    // reduce rowmax across the 16 lanes of each quad-group
#pragma unroll
    for (int d = 1; d < 16; d <<= 1)
#pragma unroll
      for (int mt = 0; mt < 2; mt++)
#pragma unroll
        for (int i = 0; i < 4; i++)
          lmax[mt][i] = fmaxf(lmax[mt][i], __shfl_xor(lmax[mt][i], d, 64));
    __syncthreads();                            // lds4 dead -> reuse for rowmax
    float* rmax = (float*)lds4;                 // [32 rows][4 waves]
    if (l16 == 0) {
#pragma unroll
      for (int mt = 0; mt < 2; mt++)
#pragma unroll
        for (int i = 0; i < 4; i++)
          rmax[(mt * 16 + quad * 4 + i) * 4 + w] = lmax[mt][i];
    }
    __syncthreads();
#pragma unroll
    for (int mt = 0; mt < 2; mt++)
#pragma unroll
      for (int i = 0; i < 4; i++) {
        int row = mt * 16 + quad * 4 + i;
        float m = fmaxf(fmaxf(rmax[row * 4 + 0], rmax[row * 4 + 1]),
                        fmaxf(rmax[row * 4 + 2], rmax[row * 4 + 3]));
        inv[mt][i] = m > 1e-30f ? 127.0f / m : 0.0f;
        if (w == 0 && l16 == 0) qsout[m0 + row] = m * (1.0f / 127.0f);
      }
  }

#pragma unroll
  for (int mt = 0; mt < 2; mt++)
#pragma unroll
    for (int i = 0; i < 4; i++) {
      int rr = m0 + mt * 16 + quad * 4 + i;     // C/D: row = quad*4 + reg
#pragma unroll
      for (int nt = 0; nt < 4; nt++) {
        int col = w * 64 + nt * 16 + l16;
        float v = acc[mt][nt][i];
        if (QOUT) {
          ((uint16_t*)hout_v)[(size_t)rr * D + col] = f2bf(v);
          int q = (int)rintf(v * inv[mt][i]);
          q8out[(size_t)rr * D + col] = (uint8_t)(q & 0xff);
        } else {
          ((float*)hout_v)[(size_t)rr * D + col] = v;
        }
      }
    }
}

extern "C" void kernel_launch(void* const* d_in, const int* in_sizes, int n_in,
                              void* d_out, int out_size, void* d_ws, size_t ws_size,
                              hipStream_t stream) {
  const float* x   = (const float*)d_in[0];
  const int*   adj = (const int*)d_in[1];
  const float* W0  = (const float*)d_in[2];
  const float* b0  = (const float*)d_in[3];
  const float* W1  = (const float*)d_in[4];
  const float* b1  = (const float*)d_in[5];
  const float* W2  = (const float*)d_in[6];
  const float* b2  = (const float*)d_in[7];
  float* out = (float*)d_out;

  // d_out doubles as scratch until layer 2 overwrites it (102.4 MB exactly):
  //   hA  bf16 [NN][D] : bytes [0, 51.2e6)          written L0, read L1
  //   hA8 int8 [NN][D] : bytes [51.2e6, 76.8e6)     written L0, read L1
  //   x8  int8 [NN][D] : bytes [76.8e6, 102.4e6)    written prep, read L0
  uint8_t*  dob = (uint8_t*)d_out;
  uint16_t* hA  = (uint16_t*)dob;
  uint8_t*  hA8 = dob + 51200000;
  uint8_t*  x8  = dob + 76800000;

  // ws (~78.8 MB): Wp x3 + hB + hB8 + scales
  uint16_t* ws  = (uint16_t*)d_ws;
  uint16_t* Wp0 = ws;
  uint16_t* Wp1 = Wp0 + D2 * D;
  uint16_t* Wp2 = Wp1 + D2 * D;
  uint16_t* hB  = Wp2 + D2 * D;                      // bf16 [NN][D]
  uint8_t*  hB8 = (uint8_t*)(hB + (size_t)NN * D);   // int8 [NN][D]
  float*    xs  = (float*)(hB8 + (size_t)NN * D);    // [NN]
  float*    hAs = xs + NN;
  float*    hBs = hAs + NN;

  prep<<<192 + NN / 4, 256, 0, stream>>>(x, x8, xs, W0, W1, W2, Wp0, Wp1, Wp2);

  const int grid = NN / MT;              // 3125 blocks, exact
  sage_layer<true,  true ><<<grid, 256, 0, stream>>>(x,  x8,  xs,  adj, Wp0, b0, hA,  hA8, hAs);
  sage_layer<false, true ><<<grid, 256, 0, stream>>>(hA, hA8, hAs, adj, Wp1, b1, hB,  hB8, hBs);
  sage_layer<false, false><<<grid, 256, 0, stream>>>(hB, hB8, hBs, adj, Wp2, b2, out, nullptr, nullptr);
}